// Round 11
// baseline (528.354 us; speedup 1.0000x reference)
//
#include <hip/hip_runtime.h>
#include <hip/hip_bf16.h>

// GraphLinear: out[b,n,o] = sum_m g[n,m] * (sum_i input[b,m,i]*W[type[m],o,i]) + bias[o]
// B=16384, N=128, DIN=DOUT=64, T=16.
// prep: bf16-convert weight/g; groups of 16 same-type m's (NG=24, idempotent pad) - R9's.
// main: PERSISTENT blocks, T3 "minimum 2-phase" pipeline:
//   1024 blocks x 16 b-row chunks each; 512 threads; LDS = ibuf[2]x32KB + hbuf 16KB
//   = 80 KB -> 2 blocks/CU. Per chunk: phase1 (LDS x -> MFMA -> hbuf) | bar |
//   STAGE next row via global_load_lds (no VGPR dest => compiler CANNOT sink it;
//   R4-R10 proved reg-staged bursts always serialize) | phase2 (hbuf -> out) | bar.
//   Staging latency hides under phase2 + sibling block. Metadata/bias hoisted out
//   of the chunk loop. f2bf via __float2bfloat16 (compiler emits v_cvt_pk_bf16_f32).

#define NN   128
#define DI   64
#define DOUT 64
#define TT   16
#define NG   24   // compile-time padded group count (max Sum ceil(n_t/16) = 23)
#define NCH  16   // b-rows per persistent block

typedef __attribute__((ext_vector_type(4))) float f32x4;
typedef __attribute__((ext_vector_type(8))) short bf16x8;

__device__ __forceinline__ short f2bf(float f) {
    return __builtin_bit_cast(short, __float2bfloat16(f));   // RTNE, packs to v_cvt_pk_bf16_f32
}

__device__ __forceinline__ bf16x8 cvt8(f32x4 a, f32x4 b) {
    bf16x8 r;
    r[0] = f2bf(a[0]); r[1] = f2bf(a[1]); r[2] = f2bf(a[2]); r[3] = f2bf(a[3]);
    r[4] = f2bf(b[0]); r[5] = f2bf(b[1]); r[6] = f2bf(b[2]); r[7] = f2bf(b[3]);
    return r;
}

__device__ __forceinline__ void load_lds16(const float* gp, float* lp) {
    __builtin_amdgcn_global_load_lds(
        (const __attribute__((address_space(1))) unsigned int*)gp,
        (__attribute__((address_space(3))) unsigned int*)lp, 16, 0, 0);
}

// Device-global scratch (rewritten every launch by prep_kernel; deterministic).
__device__ short d_wb[TT * DOUT * DI];   // bf16 weight [t][o][i], 128 KB (L1/L2-hot)
__device__ short d_gb[NN * NN];          // bf16 g [n][m], 32 KB (L1-hot)
__device__ int   d_gp[NG * 8];           // per group: m-bytes in [0..3], type in [4]

__global__ void prep_kernel(const float* __restrict__ weight,
                            const float* __restrict__ g,
                            const int*   __restrict__ ntype) {
    const int tid    = blockIdx.x * blockDim.x + threadIdx.x;
    const int stride = gridDim.x * blockDim.x;
    for (int i = tid; i < TT * DOUT * DI; i += stride) d_wb[i] = f2bf(weight[i]);
    for (int i = tid; i < NN * NN; i += stride)        d_gb[i] = f2bf(g[i]);

    if (blockIdx.x == 0) {
        __shared__ int sh_t[NN];
        const int lt = threadIdx.x;
        if (lt < NN) sh_t[lt] = ntype[lt];
        __syncthreads();
        if (lt < TT) {   // lanes 0..15 of wave 0, one type each
            int cnt = 0, m0 = 0;
            for (int m = NN - 1; m >= 0; --m)
                if (sh_t[m] == lt) { ++cnt; m0 = m; }
            const int ng = (cnt + 15) >> 4;
            int pfx = 0, total = 0;
            for (int t2 = 0; t2 < TT; ++t2) {
                const int v = __shfl(ng, t2, 64);
                if (t2 < lt) pfx += v;
                total += v;
            }
            // emit groups of 16; pad bytes pre-filled with m0 (idempotent duplicates)
            const int fill = m0 * 0x01010101;
            int Gw = pfx, cur = 0, saved = 0;
            int pk[4] = {fill, fill, fill, fill};
            int gf[4] = {fill, fill, fill, fill};
            for (int m = 0; m < NN; ++m) {
                if (sh_t[m] == lt) {
                    const int w2 = cur >> 2, s8 = (cur & 3) * 8;
                    pk[w2] = (pk[w2] & ~(0xFF << s8)) | (m << s8);
                    if (++cur == 16) {
                        for (int k2 = 0; k2 < 4; ++k2) d_gp[Gw * 8 + k2] = pk[k2];
                        d_gp[Gw * 8 + 4] = lt;
                        if (!saved) { for (int k2 = 0; k2 < 4; ++k2) gf[k2] = pk[k2]; saved = 1; }
                        ++Gw; cur = 0;
                        for (int k2 = 0; k2 < 4; ++k2) pk[k2] = fill;
                    }
                }
            }
            if (cur > 0) {
                for (int k2 = 0; k2 < 4; ++k2) d_gp[Gw * 8 + k2] = pk[k2];
                d_gp[Gw * 8 + 4] = lt;
                if (!saved) { for (int k2 = 0; k2 < 4; ++k2) gf[k2] = pk[k2]; saved = 1; }
                ++Gw;
            }
            const unsigned long long msk = __ballot(ng > 0);
            if (lt == __ffsll(msk) - 1) {
                for (int gp2 = total; gp2 < NG; ++gp2) {
                    for (int k2 = 0; k2 < 4; ++k2) d_gp[gp2 * 8 + k2] = gf[k2];
                    d_gp[gp2 * 8 + 4] = lt;
                }
            }
        }
    }
}

__global__ __launch_bounds__(512, 4)
void graph_linear_main(const float* __restrict__ input,   // [B,128,64] f32
                       const float* __restrict__ bias,    // [64] f32
                       float* __restrict__ out)           // [B,128,64] f32
{
    // ibuf[s]: one b-row, f32, LDS 16B-unit u' holds global unit u'^(m&15) (R9-proven).
    // hbuf: [o][m ^ ((o&7)<<3)] bf16.
    __shared__ float ibuf[2][NN * DI];   // 2 x 32 KiB
    __shared__ short hbuf[DOUT * NN];    // 16 KiB

    const int tid  = threadIdx.x;
    const int lane = tid & 63;
    const int wave = tid >> 6;        // 0..7
    const int lo   = lane & 15;
    const int hi   = lane >> 4;       // 0..3
    const size_t bbase = (size_t)blockIdx.x * NCH;

    // ---- hoisted wave-uniform group metadata (s_load once, live whole kernel) ----
    const int wu = __builtin_amdgcn_readfirstlane(wave);
    int mp[NG / 8][5];
#pragma unroll
    for (int it = 0; it < NG / 8; ++it) {
        const int gb = (it * 8 + wu) * 8;
#pragma unroll
        for (int k2 = 0; k2 < 5; ++k2) mp[it][k2] = d_gp[gb + k2];
    }
    // hoisted bias fragments for phase 2
    f32x4 bvv[4];
#pragma unroll
    for (int ot = 0; ot < 4; ++ot)
        bvv[ot] = *(const f32x4*)(bias + ot * 16 + hi * 4);
    const int n2 = wave * 16 + lo;    // phase-2 B-frag col (n)

    // ---- prologue: stage chunk 0 into buffer 0 ----
    {
        const float* src = input + bbase * (NN * DI);
#pragma unroll
        for (int q = 0; q < 4; ++q) {
            const int ck = wave * 4 + q;
            const int U  = ck * 64 + lane;
            const int m  = U >> 4;
            const int u  = (U & 15) ^ (m & 15);
            load_lds16(src + m * 64 + u * 4, &ibuf[0][ck * 256]);
        }
    }
    __syncthreads();

    int cur = 0;
#pragma unroll 1
    for (int c = 0; c < NCH; ++c) {
        // ---- phase 1: grouped MFMA from ibuf[cur] -> hbuf ----
#pragma unroll
        for (int it = 0; it < NG / 8; ++it) {
            const int p0 = mp[it][0], p1 = mp[it][1];
            const int p2 = mp[it][2], p3 = mp[it][3];
            const int t  = mp[it][4];

            const int ps = (lo < 8) ? ((lo < 4) ? p0 : p1) : ((lo < 12) ? p2 : p3);
            const int mA = (ps >> ((lo & 3) * 8)) & 0xFF;
            const int sA = mA & 15;
            const float* arow = &ibuf[cur][mA * DI];
            const f32x4 r0 = *(const f32x4*)&arow[((hi * 2)     ^ sA) * 4];
            const f32x4 r1 = *(const f32x4*)&arow[((hi * 2 + 1) ^ sA) * 4];
            const f32x4 r2 = *(const f32x4*)&arow[((hi * 2 + 8) ^ sA) * 4];
            const f32x4 r3 = *(const f32x4*)&arow[((hi * 2 + 9) ^ sA) * 4];
            const bf16x8 a0 = cvt8(r0, r1);           // k = 0..31
            const bf16x8 a1 = cvt8(r2, r3);           // k = 32..63

            const short* wrow = d_wb + t * (DOUT * DI);
            f32x4 hacc[4];
#pragma unroll
            for (int ot = 0; ot < 4; ++ot) hacc[ot] = 0.0f;
#pragma unroll
            for (int ot = 0; ot < 4; ++ot) {
                const int o = ot * 16 + lo;           // B-frag col
                const bf16x8 w0 = *(const bf16x8*)(wrow + o * DI + hi * 8);
                hacc[ot] = __builtin_amdgcn_mfma_f32_16x16x32_bf16(a0, w0, hacc[ot], 0, 0, 0);
                const bf16x8 w1 = *(const bf16x8*)(wrow + o * DI + 32 + hi * 8);
                hacc[ot] = __builtin_amdgcn_mfma_f32_16x16x32_bf16(a1, w1, hacc[ot], 0, 0, 0);
            }
            // D rows r = hi*4+j -> group slot r -> m = byte j of p[hi]. Duplicates idempotent.
            const int pst = (hi < 2) ? ((hi == 0) ? p0 : p1) : ((hi == 2) ? p2 : p3);
#pragma unroll
            for (int ot = 0; ot < 4; ++ot) {
                const int o   = ot * 16 + lo;
                const int swz = (o & 7) << 3;
#pragma unroll
                for (int j = 0; j < 4; ++j) {
                    const int mS = (pst >> (8 * j)) & 0xFF;
                    hbuf[o * NN + (mS ^ swz)] = f2bf(hacc[ot][j]);
                }
            }
        }
        __syncthreads();   // hbuf ready; ibuf[cur] fully consumed

        // ---- stage NEXT chunk into ibuf[cur^1] (DMA; hides under phase 2) ----
        if (c + 1 < NCH) {
            const float* src = input + (bbase + c + 1) * (NN * DI);
#pragma unroll
            for (int q = 0; q < 4; ++q) {
                const int ck = wave * 4 + q;
                const int U  = ck * 64 + lane;
                const int m  = U >> 4;
                const int u  = (U & 15) ^ (m & 15);
                load_lds16(src + m * 64 + u * 4, &ibuf[cur ^ 1][ck * 256]);
            }
        }

        // ---- phase 2: out[b, n, :] = g @ h + bias ----
        {
            f32x4 acc[4];
#pragma unroll
            for (int ot = 0; ot < 4; ++ot) acc[ot] = bvv[ot];
#pragma unroll
            for (int cc = 0; cc < 4; ++cc) {
                const bf16x8 gfr = *(const bf16x8*)(d_gb + n2 * NN + cc * 32 + hi * 8);
#pragma unroll
                for (int ot = 0; ot < 4; ++ot) {
                    const int o   = ot * 16 + lo;     // A-frag row = o
                    const int pos = (cc * 32 + hi * 8) ^ ((o & 7) << 3);
                    const bf16x8 hfr = *(const bf16x8*)&hbuf[o * NN + pos];
                    acc[ot] = __builtin_amdgcn_mfma_f32_16x16x32_bf16(hfr, gfr, acc[ot], 0, 0, 0);
                }
            }
            float* orow = out + ((bbase + c) * NN + n2) * DOUT;
#pragma unroll
            for (int ot = 0; ot < 4; ++ot)
                *(f32x4*)&orow[ot * 16 + hi * 4] = acc[ot];
        }
        __syncthreads();   // drains staging DMA + stores; hbuf/ibuf safe to reuse
        cur ^= 1;
    }
}

extern "C" void kernel_launch(void* const* d_in, const int* in_sizes, int n_in,
                              void* d_out, int out_size, void* d_ws, size_t ws_size,
                              hipStream_t stream) {
    const float* input  = (const float*)d_in[0];
    const float* g      = (const float*)d_in[1];
    const float* weight = (const float*)d_in[2];
    const float* bias   = (const float*)d_in[3];
    const int*   ntype  = (const int*)d_in[4];
    float* out = (float*)d_out;

    const int B = in_sizes[0] / (NN * DI);   // 16384

    hipLaunchKernelGGL(prep_kernel, dim3(32), dim3(256), 0, stream, weight, g, ntype);
    hipLaunchKernelGGL(graph_linear_main, dim3(B / NCH), dim3(512), 0, stream,
                       input, bias, out);
}

// Round 12
// 237.783 us; speedup vs baseline: 2.2220x; 2.2220x over previous
//
#include <hip/hip_runtime.h>
#include <hip/hip_bf16.h>

// GraphLinear: out[b,n,o] = sum_m g[n,m] * (sum_i input[b,m,i]*W[type[m],o,i]) + bias[o]
// B=16384, N=128, DIN=DOUT=64, T=16.
// prep: bf16-convert weight/g; groups of 16 same-type m's (NG=24, idempotent pad).
// main: persistent 512 blocks x NCH=32 b-rows; 512 threads (8 waves); 96 KB LDS;
//   launch_bounds(512,2) -> 256-VGPR budget. ALL repeated global reads hoisted to
//   registers ONCE per block (W-frags 96 VGPR, g-frags 16, bias 16, metadata 15):
//   the chunk loop contains ZERO global loads (R4-R11: reg-staged global loads in
//   loops are serialized at full latency by hipcc - the entire plateau).
//   Software pipeline, ONE barrier per chunk:
//     [ DMA(c+1) -> ibuf[(c+1)&1] ; phase1(c): ibuf->MFMA(Wregs)->hbuf[c&1] ;
//       phase2(c-1): hbuf[(c-1)&1] + g-regs -> out ] ; barrier.
//   DMA has a full chunk (~phase1+phase2) to land before the barrier drain.

#define NN   128
#define DI   64
#define DOUT 64
#define TT   16
#define NG   24   // compile-time padded group count (max Sum ceil(n_t/16) = 23)
#define NCH  32   // b-rows per persistent block

typedef __attribute__((ext_vector_type(4))) float f32x4;
typedef __attribute__((ext_vector_type(8))) short bf16x8;

__device__ __forceinline__ short f2bf(float f) {
    return __builtin_bit_cast(short, __float2bfloat16(f));   // RTNE, packs to v_cvt_pk_bf16_f32
}

__device__ __forceinline__ bf16x8 cvt8(f32x4 a, f32x4 b) {
    bf16x8 r;
    r[0] = f2bf(a[0]); r[1] = f2bf(a[1]); r[2] = f2bf(a[2]); r[3] = f2bf(a[3]);
    r[4] = f2bf(b[0]); r[5] = f2bf(b[1]); r[6] = f2bf(b[2]); r[7] = f2bf(b[3]);
    return r;
}

__device__ __forceinline__ void load_lds16(const float* gp, float* lp) {
    __builtin_amdgcn_global_load_lds(
        (const __attribute__((address_space(1))) unsigned int*)gp,
        (__attribute__((address_space(3))) unsigned int*)lp, 16, 0, 0);
}

// Device-global scratch (rewritten every launch by prep_kernel; deterministic).
__device__ short d_wb[TT * DOUT * DI];   // bf16 weight [t][o][i], 128 KB
__device__ short d_gb[NN * NN];          // bf16 g [n][m], 32 KB
__device__ int   d_gp[NG * 8];           // per group: m-bytes in [0..3], type in [4]

__global__ void prep_kernel(const float* __restrict__ weight,
                            const float* __restrict__ g,
                            const int*   __restrict__ ntype) {
    const int tid    = blockIdx.x * blockDim.x + threadIdx.x;
    const int stride = gridDim.x * blockDim.x;
    for (int i = tid; i < TT * DOUT * DI; i += stride) d_wb[i] = f2bf(weight[i]);
    for (int i = tid; i < NN * NN; i += stride)        d_gb[i] = f2bf(g[i]);

    if (blockIdx.x == 0) {
        __shared__ int sh_t[NN];
        const int lt = threadIdx.x;
        if (lt < NN) sh_t[lt] = ntype[lt];
        __syncthreads();
        if (lt < TT) {   // lanes 0..15 of wave 0, one type each
            int cnt = 0, m0 = 0;
            for (int m = NN - 1; m >= 0; --m)
                if (sh_t[m] == lt) { ++cnt; m0 = m; }
            const int ng = (cnt + 15) >> 4;
            int pfx = 0, total = 0;
            for (int t2 = 0; t2 < TT; ++t2) {
                const int v = __shfl(ng, t2, 64);
                if (t2 < lt) pfx += v;
                total += v;
            }
            const int fill = m0 * 0x01010101;
            int Gw = pfx, cur = 0, saved = 0;
            int pk[4] = {fill, fill, fill, fill};
            int gf[4] = {fill, fill, fill, fill};
            for (int m = 0; m < NN; ++m) {
                if (sh_t[m] == lt) {
                    const int w2 = cur >> 2, s8 = (cur & 3) * 8;
                    pk[w2] = (pk[w2] & ~(0xFF << s8)) | (m << s8);
                    if (++cur == 16) {
                        for (int k2 = 0; k2 < 4; ++k2) d_gp[Gw * 8 + k2] = pk[k2];
                        d_gp[Gw * 8 + 4] = lt;
                        if (!saved) { for (int k2 = 0; k2 < 4; ++k2) gf[k2] = pk[k2]; saved = 1; }
                        ++Gw; cur = 0;
                        for (int k2 = 0; k2 < 4; ++k2) pk[k2] = fill;
                    }
                }
            }
            if (cur > 0) {
                for (int k2 = 0; k2 < 4; ++k2) d_gp[Gw * 8 + k2] = pk[k2];
                d_gp[Gw * 8 + 4] = lt;
                if (!saved) { for (int k2 = 0; k2 < 4; ++k2) gf[k2] = pk[k2]; saved = 1; }
                ++Gw;
            }
            const unsigned long long msk = __ballot(ng > 0);
            if (lt == __ffsll(msk) - 1) {
                for (int gp2 = total; gp2 < NG; ++gp2) {
                    for (int k2 = 0; k2 < 4; ++k2) d_gp[gp2 * 8 + k2] = gf[k2];
                    d_gp[gp2 * 8 + 4] = lt;
                }
            }
        }
    }
}

__global__ __launch_bounds__(512, 2)
void graph_linear_main(const float* __restrict__ input,   // [B,128,64] f32
                       const float* __restrict__ bias,    // [64] f32
                       float* __restrict__ out)           // [B,128,64] f32
{
    // ibuf: one b-row f32; LDS 16B-unit U holds global unit (U&15)^(m&15) of row m (R9).
    // hbuf: [o][m ^ ((o&7)<<3)] bf16. Both double-buffered.
    __shared__ float ibuf0[NN * DI];     // 32 KiB
    __shared__ float ibuf1[NN * DI];     // 32 KiB
    __shared__ short hbuf0[DOUT * NN];   // 16 KiB
    __shared__ short hbuf1[DOUT * NN];   // 16 KiB

    const int tid  = threadIdx.x;
    const int lane = tid & 63;
    const int wave = tid >> 6;        // 0..7
    const int lo   = lane & 15;
    const int hi   = lane >> 4;       // 0..3
    const size_t bbase = (size_t)blockIdx.x * NCH;
    const float* const inblk = input + bbase * (NN * DI);

    // ======== block-start hoists (the ONLY global reads besides DMA/stores) ========
    const int wu = __builtin_amdgcn_readfirstlane(wave);
    int mp[NG / 8][5];
#pragma unroll
    for (int it = 0; it < NG / 8; ++it) {
        const int gb = (it * 8 + wu) * 8;
#pragma unroll
        for (int k2 = 0; k2 < 5; ++k2) mp[it][k2] = d_gp[gb + k2];
    }
    // W-fragments for this wave's 3 groups: 24 x bf16x8 = 96 VGPR, loaded once.
    bf16x8 wfr[NG / 8][8];
#pragma unroll
    for (int it = 0; it < NG / 8; ++it) {
        const short* wrow = d_wb + mp[it][4] * (DOUT * DI);
#pragma unroll
        for (int ot = 0; ot < 4; ++ot) {
            wfr[it][2 * ot]     = *(const bf16x8*)(wrow + (ot * 16 + lo) * DI + hi * 8);
            wfr[it][2 * ot + 1] = *(const bf16x8*)(wrow + (ot * 16 + lo) * DI + 32 + hi * 8);
        }
    }
    // g-fragments for this wave's phase-2 n-tile (n2): 16 VGPR, loaded once.
    const int n2 = wave * 16 + lo;
    bf16x8 gfr[4];
#pragma unroll
    for (int cc = 0; cc < 4; ++cc)
        gfr[cc] = *(const bf16x8*)(d_gb + n2 * NN + cc * 32 + hi * 8);
    // bias fragments: 16 VGPR.
    f32x4 bvv[4];
#pragma unroll
    for (int ot = 0; ot < 4; ++ot)
        bvv[ot] = *(const f32x4*)(bias + ot * 16 + hi * 4);

    // ======== helpers ========
    auto STAGE = [&](float* dst, const float* srcrow) {
#pragma unroll
        for (int q = 0; q < 4; ++q) {
            const int ck = wave * 4 + q;
            const int U  = ck * 64 + lane;
            const int m  = U >> 4;
            const int u  = (U & 15) ^ (m & 15);
            load_lds16(srcrow + m * 64 + u * 4, dst + ck * 256);
        }
    };
    auto PHASE1 = [&](const float* ib, short* hb) {
#pragma unroll
        for (int it = 0; it < NG / 8; ++it) {
            const int p0 = mp[it][0], p1 = mp[it][1];
            const int p2 = mp[it][2], p3 = mp[it][3];
            const int ps = (lo < 8) ? ((lo < 4) ? p0 : p1) : ((lo < 12) ? p2 : p3);
            const int mA = (ps >> ((lo & 3) * 8)) & 0xFF;
            const int sA = mA & 15;
            const float* arow = ib + mA * DI;
            const f32x4 r0 = *(const f32x4*)&arow[((hi * 2)     ^ sA) * 4];
            const f32x4 r1 = *(const f32x4*)&arow[((hi * 2 + 1) ^ sA) * 4];
            const f32x4 r2 = *(const f32x4*)&arow[((hi * 2 + 8) ^ sA) * 4];
            const f32x4 r3 = *(const f32x4*)&arow[((hi * 2 + 9) ^ sA) * 4];
            const bf16x8 a0 = cvt8(r0, r1);           // k = 0..31
            const bf16x8 a1 = cvt8(r2, r3);           // k = 32..63

            f32x4 hacc[4];
#pragma unroll
            for (int ot = 0; ot < 4; ++ot) hacc[ot] = 0.0f;
#pragma unroll
            for (int ot = 0; ot < 4; ++ot) {
                hacc[ot] = __builtin_amdgcn_mfma_f32_16x16x32_bf16(a0, wfr[it][2 * ot],     hacc[ot], 0, 0, 0);
                hacc[ot] = __builtin_amdgcn_mfma_f32_16x16x32_bf16(a1, wfr[it][2 * ot + 1], hacc[ot], 0, 0, 0);
            }
            const int pst = (hi < 2) ? ((hi == 0) ? p0 : p1) : ((hi == 2) ? p2 : p3);
#pragma unroll
            for (int ot = 0; ot < 4; ++ot) {
                const int o   = ot * 16 + lo;
                const int swz = (o & 7) << 3;
#pragma unroll
                for (int j = 0; j < 4; ++j) {
                    const int mS = (pst >> (8 * j)) & 0xFF;
                    hb[o * NN + (mS ^ swz)] = f2bf(hacc[ot][j]);
                }
            }
        }
    };
    auto PHASE2 = [&](const short* hb, float* orow) {
        f32x4 acc[4];
#pragma unroll
        for (int ot = 0; ot < 4; ++ot) acc[ot] = bvv[ot];
#pragma unroll
        for (int cc = 0; cc < 4; ++cc) {
#pragma unroll
            for (int ot = 0; ot < 4; ++ot) {
                const int o   = ot * 16 + lo;
                const int pos = (cc * 32 + hi * 8) ^ ((o & 7) << 3);
                const bf16x8 hfr = *(const bf16x8*)&hb[o * NN + pos];
                acc[ot] = __builtin_amdgcn_mfma_f32_16x16x32_bf16(hfr, gfr[cc], acc[ot], 0, 0, 0);
            }
        }
#pragma unroll
        for (int ot = 0; ot < 4; ++ot)
            *(f32x4*)&orow[ot * 16 + hi * 4] = acc[ot];
    };

    // ======== software-pipelined chunk loop: one barrier per chunk ========
    STAGE(ibuf0, inblk);
    __syncthreads();
    STAGE(ibuf1, inblk + NN * DI);
    PHASE1(ibuf0, hbuf0);
    __syncthreads();

#pragma unroll 1
    for (int c = 1; c < NCH; ++c) {
        if (c + 1 < NCH)
            STAGE((c & 1) ? ibuf0 : ibuf1, inblk + (size_t)(c + 1) * (NN * DI));
        PHASE1((c & 1) ? ibuf1 : ibuf0, (c & 1) ? hbuf1 : hbuf0);
        PHASE2((c & 1) ? hbuf0 : hbuf1,
               out + ((bbase + c - 1) * NN + n2) * DOUT);
        __syncthreads();
    }
    PHASE2(hbuf1, out + ((bbase + NCH - 1) * NN + n2) * DOUT);   // (NCH-1)&1 = 1
}

extern "C" void kernel_launch(void* const* d_in, const int* in_sizes, int n_in,
                              void* d_out, int out_size, void* d_ws, size_t ws_size,
                              hipStream_t stream) {
    const float* input  = (const float*)d_in[0];
    const float* g      = (const float*)d_in[1];
    const float* weight = (const float*)d_in[2];
    const float* bias   = (const float*)d_in[3];
    const int*   ntype  = (const int*)d_in[4];
    float* out = (float*)d_out;

    const int B = in_sizes[0] / (NN * DI);   // 16384

    hipLaunchKernelGGL(prep_kernel, dim3(32), dim3(256), 0, stream, weight, g, ntype);
    hipLaunchKernelGGL(graph_linear_main, dim3(B / NCH), dim3(512), 0, stream,
                       input, bias, out);
}